// Round 12
// baseline (297.928 us; speedup 1.0000x reference)
//
#include <hip/hip_runtime.h>
#include <hip/hip_bf16.h>

// LSTM: I=32, H=64, O=8, B=4096, T=256, fused single kernel.
// Round 17: 2 blocks/CU (BR=8 mirror, grid=512) + R12 math + PHASE STAGGER.
//  - Theory: R11/R14 TLP failures were phase-locking — co-scheduled blocks
//    run in-phase and stall simultaneously (R11 wall == Sum-issue + full
//    stall, zero interleave). The serial chain (~800cy/step) can only be
//    hidden by a block in ANTI-phase. Force it: per-block s_sleep stagger
//    (hashed blockIdx, 0..~450cy) before the main loop. Offsets are
//    neutral-stable (equal periods) so the stagger persists.
//  - Structure: R6/R11-proven BR=8 permuted-mirror full-M (acc[g][0..1] are
//    real cells for every lane), 4 waves, one lgkm-only barrier per step.
//  - Math: R12-proven — weights/bias pre-scaled by -log2e (i,f,o) and
//    -2log2e (g) so MFMA emits exp2-ready args; combined-rcp activations
//    (8 trans/cell); preacc x-proj pipeline (post-barrier chain = 2 MFMAs).

#define T_LEN 256
#define I_SZ  32
#define H_SZ  64
#define O_SZ  8
#define BR    8
#define HS    72   // h row stride in shorts

typedef __attribute__((ext_vector_type(8))) short short8;
typedef __attribute__((ext_vector_type(4))) float f32x4;
typedef __attribute__((ext_vector_type(2))) float f32x2;

static __device__ __forceinline__ unsigned fbits(float f) {
    union { float f; unsigned u; } v; v.f = f; return v.u;
}
// two floats -> packed bf16x2 (truncation): elem0 = lo, elem1 = hi
static __device__ __forceinline__ unsigned pk2t(float lo, float hi) {
    return __builtin_amdgcn_perm(fbits(hi), fbits(lo), 0x07060302u);
}
static __device__ __forceinline__ short f2bf_rne(float f) {   // init-time only
    union { __hip_bfloat16 b; short s; } u;
    u.b = __float2bfloat16(f);
    return u.s;
}
static __device__ __forceinline__ f32x2 rcp2(f32x2 d) {
    f32x2 r;
    r.x = __builtin_amdgcn_rcpf(d.x);
    r.y = __builtin_amdgcn_rcpf(d.y);
    return r;
}
static __device__ __forceinline__ f32x2 exp2_2(f32x2 m) {
    f32x2 e;
    e.x = __builtin_amdgcn_exp2f(m.x);
    e.y = __builtin_amdgcn_exp2f(m.y);
    return e;
}
static __device__ __forceinline__ f32x2 clamp2(f32x2 x, float lo, float hi) {
    f32x2 r;
    r.x = __builtin_amdgcn_fmed3f(x.x, lo, hi);
    r.y = __builtin_amdgcn_fmed3f(x.y, lo, hi);
    return r;
}
static __device__ __forceinline__ f32x2 fma2(f32x2 a, f32x2 b, f32x2 c) {
    return __builtin_elementwise_fma(a, b, c);
}
// LDS-only barrier (R16-proven): drain ds ops, s_barrier. No vmcnt drain.
static __device__ __forceinline__ void lds_barrier() {
    asm volatile("s_waitcnt lgkmcnt(0)\n\ts_barrier" ::: "memory");
}

#define LOG2E     1.4426950408889634f
#define TWO_LOG2E 2.8853900817779268f
#define ECLAMP    28.8f   // exp2-domain clamp: tanh saturation at |x|=10

__global__ __launch_bounds__(256, 2)
void lstm_fused_kernel(const float* __restrict__ x,
                       const float* __restrict__ W_ih,
                       const float* __restrict__ W_hh,
                       const float* __restrict__ b_ih,
                       const float* __restrict__ b_hh,
                       const float* __restrict__ W_fc,
                       const float* __restrict__ b_fc,
                       float* __restrict__ out)
{
    __shared__ short hbuf[2][8][HS];   // h double buffer, bf16, rows 0..7
    __shared__ float Hf[BR][64];

    const int tid  = threadIdx.x;
    const int wave = tid >> 6;
    const int lane = tid & 63;
    const int quad = lane >> 4;
    const int nlow = lane & 15;
    const int jw   = wave * 16 + nlow;   // gate-col this lane's tiles own
    const int b0   = blockIdx.x * BR;

    // Permuted mirror row for A-reads: {0..7, 2,3,2,3, 6,7,6,7}
    const int fr = (nlow < 8) ? nlow : (((nlow & 4) ? 6 : 2) + (nlow & 1));
    // Cell rows this lane owns (uses acc[0],acc[1]): q0->0,1 q1->4,5 q2->2,3 q3->6,7
    const int ra = ((quad & 1) << 2) | (quad & 2);

    // ---- B fragments, PRE-SCALED so MFMA emits exp2-ready args (R12).
    short8 bfrag[4][3];
    f32x4  biasf[4];
    for (int g = 0; g < 4; ++g) {
        const float scale = (g == 2) ? -TWO_LOG2E : -LOG2E;
        const int col = g * 64 + jw;
        {
            const float* wr = W_ih + col * I_SZ + quad * 8;
            short8 f;
            #pragma unroll
            for (int e = 0; e < 8; ++e) f[e] = f2bf_rne(scale * wr[e]);
            bfrag[g][0] = f;
        }
        #pragma unroll
        for (int kt = 1; kt < 3; ++kt) {
            const float* wr = W_hh + col * H_SZ + (kt - 1) * 32 + quad * 8;
            short8 f;
            #pragma unroll
            for (int e = 0; e < 8; ++e) f[e] = f2bf_rne(scale * wr[e]);
            bfrag[g][kt] = f;
        }
        const float bg = scale * (b_ih[col] + b_hh[col]);
        biasf[g] = (f32x4){bg, bg, bg, bg};
    }

    // ---- zero h buffers (h0 = 0)
    for (int q = tid; q < 2 * 8 * HS; q += 256) ((short*)hbuf)[q] = (short)0;

    // ---- x chunk machinery: lane owns x[b0+fr][t][quad*8 .. +7].
    const float* xb = x + ((size_t)(b0 + fr) * T_LEN) * I_SZ + quad * 8;

    float4 nx[16];                        // next-chunk fp32 (8 steps x 8 floats)
    short8 sc[8];                         // current-chunk bf16 fragments
    #pragma unroll
    for (int s = 0; s < 8; ++s) {
        nx[2*s]   = *(const float4*)(xb + s * I_SZ);
        nx[2*s+1] = *(const float4*)(xb + s * I_SZ + 4);
    }
    #pragma unroll
    for (int s = 0; s < 8; ++s) {
        union { uint4 u; short8 v; } w;
        w.u.x = pk2t(nx[2*s].x,   nx[2*s].y);
        w.u.y = pk2t(nx[2*s].z,   nx[2*s].w);
        w.u.z = pk2t(nx[2*s+1].x, nx[2*s+1].y);
        w.u.w = pk2t(nx[2*s+1].z, nx[2*s+1].w);
        sc[s] = w.v;
    }

    // LDS addresses
    const short* rb[2] = { &hbuf[0][fr][quad * 8], &hbuf[1][fr][quad * 8] };
    short*       wb[2] = { &hbuf[0][ra][jw],       &hbuf[1][ra][jw] };

    f32x2 cc = {0.f, 0.f};
    f32x2 hh = {0.f, 0.f};

    // ---- x-projection pipeline: preacc[g] for the upcoming step.
    f32x4 preacc[4];
    #pragma unroll
    for (int g = 0; g < 4; ++g)
        preacc[g] = __builtin_amdgcn_mfma_f32_16x16x32_bf16(sc[0], bfrag[g][0], biasf[g], 0, 0, 0);

    // ---- PHASE STAGGER: break co-resident-block phase symmetry.
    // Hashed blockIdx -> 0..7 sleeps of ~64cy. Block-uniform (all waves),
    // so the whole block shifts phase vs its CU neighbor.
    {
        const int dly = (blockIdx.x ^ (blockIdx.x >> 3) ^ (blockIdx.x >> 6)) & 7;
        for (int i = 0; i < dly; ++i) asm volatile("s_sleep 1");
    }

    for (int ch = 0; ch < 32; ++ch) {
        #pragma unroll
        for (int tc = 0; tc < 8; ++tc) {
            const int t = ch * 8 + tc;

            lds_barrier();               // h_{t-1} (and at t=0 the zeroing) visible

            // h fragments: A[m][k = 32*kt + quad*8 + e], rows via fr
            const short* hr = rb[t & 1];
            short8 a1 = *(const short8*)(hr);        // h cols  0..31
            short8 a2 = *(const short8*)(hr + 32);   // h cols 32..63

            // issue next chunk's global loads early in the chunk
            if (tc == 0 && ch + 1 < 32) {
                const float* nxt = xb + (t + 8) * I_SZ;
                #pragma unroll
                for (int s = 0; s < 8; ++s) {
                    nx[2*s]   = *(const float4*)(nxt + s * I_SZ);
                    nx[2*s+1] = *(const float4*)(nxt + s * I_SZ + 4);
                }
            }

            // post-barrier dependent chain: 2 MFMAs deep (C = preacc).
            f32x4 acc[4];
            #pragma unroll
            for (int g = 0; g < 4; ++g) {
                f32x4 a = __builtin_amdgcn_mfma_f32_16x16x32_bf16(a1, bfrag[g][1], preacc[g], 0, 0, 0);
                a = __builtin_amdgcn_mfma_f32_16x16x32_bf16(a2, bfrag[g][2], a, 0, 0, 0);
                acc[g] = a;
            }

            // convert next chunk once its loads landed (7 steps of cover)
            if (tc == 7 && ch + 1 < 32) {
                #pragma unroll
                for (int s = 0; s < 8; ++s) {
                    union { uint4 u; short8 v; } w;
                    w.u.x = pk2t(nx[2*s].x,   nx[2*s].y);
                    w.u.y = pk2t(nx[2*s].z,   nx[2*s].w);
                    w.u.z = pk2t(nx[2*s+1].x, nx[2*s+1].y);
                    w.u.w = pk2t(nx[2*s+1].z, nx[2*s+1].w);
                    sc[s] = w.v;
                }
            }

            // x-projection for step t+1: independent filler.
            const short8 nax = sc[(tc + 1) & 7];
            #pragma unroll
            for (int g = 0; g < 4; ++g)
                preacc[g] = __builtin_amdgcn_mfma_f32_16x16x32_bf16(nax, bfrag[g][0], biasf[g], 0, 0, 0);

            // ---- cell update: cells (ra, jw), (ra+1, jw); exp2-ready args.
            f32x2 pi = {acc[0][0], acc[0][1]};
            f32x2 pf = {acc[1][0], acc[1][1]};
            f32x2 pg = {acc[2][0], acc[2][1]};
            f32x2 po = {acc[3][0], acc[3][1]};

            f32x2 ei = exp2_2(pi);
            f32x2 ef = exp2_2(pf);
            f32x2 eg = exp2_2(clamp2(pg, -ECLAMP, ECLAMP));
            f32x2 eo = exp2_2(po);
            f32x2 fv = rcp2(ef + 1.0f);                               // sigmoid(f)
            f32x2 ig = (1.0f - eg) * rcp2((ei + 1.0f) * (eg + 1.0f)); // sig(i)*tanh(g)
            cc = fma2(fv, cc, ig);
            f32x2 ec = exp2_2(clamp2(cc * (-TWO_LOG2E), -ECLAMP, ECLAMP));
            hh = (1.0f - ec) * rcp2((eo + 1.0f) * (ec + 1.0f));       // sig(o)*tanh(c)

            short* hw = wb[(t + 1) & 1];
            hw[0]  = (short)((fbits(hh.x) + 0x8000u) >> 16);
            hw[HS] = (short)((fbits(hh.y) + 0x8000u) >> 16);
        }
    }

    // ---- epilogue: out[b0+r][o] = h_T[r] . W_fc[o] + b_fc[o]  (fp32 h)
    Hf[ra][jw]     = hh.x;
    Hf[ra + 1][jw] = hh.y;
    __syncthreads();

    if (tid < BR * O_SZ) {               // 64 threads
        const int r = tid >> 3;
        const int o = tid & 7;
        const float* wf = W_fc + o * H_SZ;
        float acc = b_fc[o];
        #pragma unroll
        for (int jx = 0; jx < H_SZ; ++jx) acc += Hf[r][jx] * wf[jx];
        out[(size_t)(b0 + r) * O_SZ + o] = acc;
    }
}

extern "C" void kernel_launch(void* const* d_in, const int* in_sizes, int n_in,
                              void* d_out, int out_size, void* d_ws, size_t ws_size,
                              hipStream_t stream) {
    const float* x    = (const float*)d_in[0];
    const float* W_ih = (const float*)d_in[1];
    const float* W_hh = (const float*)d_in[2];
    const float* b_ih = (const float*)d_in[3];
    const float* b_hh = (const float*)d_in[4];
    const float* W_fc = (const float*)d_in[5];
    const float* b_fc = (const float*)d_in[6];
    float* out = (float*)d_out;

    const int B = 4096;
    lstm_fused_kernel<<<dim3(B / BR), dim3(256), 0, stream>>>(
        x, W_ih, W_hh, b_ih, b_hh, W_fc, b_fc, out);
}

// Round 13
// 282.223 us; speedup vs baseline: 1.0556x; 1.0556x over previous
//
#include <hip/hip_runtime.h>
#include <hip/hip_bf16.h>

// LSTM: I=32, H=64, O=8, B=4096, T=256, fused single kernel.
// Round 18: RESTORE THE CHAMPION (R12, measured 144.7us, passed).
// Session conclusion after 13 measured rounds:
//  - Structure: BR=16 full-M MFMA, grid 256, 1 blk/CU, 1 wave/SIMD,
//    one __syncthreads per step, h bf16 in LDS double buffer.
//  - Math: weights/bias pre-scaled by -log2e (i,f,o) / -2log2e (g) so MFMA
//    emits exp2-ready gate args; combined-rcp activations (8 trans/cell);
//    preacc x-proj pipeline (post-barrier dependent chain = 2 MFMAs).
//  - Proven dead ends (all measured): 2 blk/CU mirror (R11 179, R17 167 —
//    interleave works but mirror-MFMA duplication eats it), 8-wave gate
//    split (R13 218 — 2nd barrier), 8-wave transposed-GEMM (R14 187 —
//    convoy + conflict amplification), pk-f32 inline asm (R8/R9 — wrong
//    results, MFMA->asm hazard class), bank permutation / preacc shadow /
//    de-burst / lgkm-only barrier (R15/R16 — all neutral).
//  - Floor analysis: 1360 cy/step = ~690 cy issue (trans 256 + VALU ~300 +
//    MFMA ~80 + mem) + ~670 cy serial recurrence latency (LDS round-trip +
//    barrier + MFMA dep + activation chain) unhideable at 1 wave/SIMD;
//    B = 4096 = exactly 16 rows x 256 CUs leaves no co-residency headroom
//    without M<16 MFMA waste or idle SIMDs.

#define T_LEN 256
#define I_SZ  32
#define H_SZ  64
#define O_SZ  8
#define BR    16
#define HS    72   // h row stride in shorts

typedef __attribute__((ext_vector_type(8))) short short8;
typedef __attribute__((ext_vector_type(4))) float f32x4;

static __device__ __forceinline__ unsigned fbits(float f) {
    union { float f; unsigned u; } v; v.f = f; return v.u;
}
// two floats -> packed bf16x2 (truncation): elem0 = lo, elem1 = hi
static __device__ __forceinline__ unsigned pk2t(float lo, float hi) {
    return __builtin_amdgcn_perm(fbits(hi), fbits(lo), 0x07060302u);
}
static __device__ __forceinline__ short f2bf_rne(float f) {   // init-time only
    union { __hip_bfloat16 b; short s; } u;
    u.b = __float2bfloat16(f);
    return u.s;
}
static __device__ __forceinline__ f32x4 rcp4(f32x4 d) {
    f32x4 r;
    r.x = __builtin_amdgcn_rcpf(d.x);
    r.y = __builtin_amdgcn_rcpf(d.y);
    r.z = __builtin_amdgcn_rcpf(d.z);
    r.w = __builtin_amdgcn_rcpf(d.w);
    return r;
}
static __device__ __forceinline__ f32x4 exp2_4(f32x4 m) {
    f32x4 e;
    e.x = __builtin_amdgcn_exp2f(m.x);
    e.y = __builtin_amdgcn_exp2f(m.y);
    e.z = __builtin_amdgcn_exp2f(m.z);
    e.w = __builtin_amdgcn_exp2f(m.w);
    return e;
}
static __device__ __forceinline__ f32x4 clamp4(f32x4 x, float lo, float hi) {
    f32x4 r;
    r.x = __builtin_amdgcn_fmed3f(x.x, lo, hi);
    r.y = __builtin_amdgcn_fmed3f(x.y, lo, hi);
    r.z = __builtin_amdgcn_fmed3f(x.z, lo, hi);
    r.w = __builtin_amdgcn_fmed3f(x.w, lo, hi);
    return r;
}
static __device__ __forceinline__ f32x4 fma4(f32x4 a, f32x4 b, f32x4 c) {
    return __builtin_elementwise_fma(a, b, c);
}

#define LOG2E     1.4426950408889634f
#define TWO_LOG2E 2.8853900817779268f
#define ECLAMP    28.8f   // exp2-domain clamp: tanh saturation at |x|=10

__global__ __launch_bounds__(256, 1)
void lstm_fused_kernel(const float* __restrict__ x,
                       const float* __restrict__ W_ih,
                       const float* __restrict__ W_hh,
                       const float* __restrict__ b_ih,
                       const float* __restrict__ b_hh,
                       const float* __restrict__ W_fc,
                       const float* __restrict__ b_fc,
                       float* __restrict__ out)
{
    __shared__ short hbuf[2][BR][HS];   // h double buffer, bf16, 16 real rows
    __shared__ float Hf[BR][64];

    const int tid   = threadIdx.x;
    const int wave  = tid >> 6;
    const int lane  = tid & 63;
    const int quad  = lane >> 4;
    const int nlow  = lane & 15;
    const int jw    = wave * 16 + nlow;  // hidden col this lane's tiles own
    const int rbase = quad * 4;          // D rows this lane owns (real rows)
    const int b0    = blockIdx.x * BR;

    // ---- B fragments, PRE-SCALED so MFMA emits exp2-ready args.
    // gates 0,1,3 (i,f,o): scale -log2e ; gate 2 (g): scale -2log2e.
    short8 bfrag[4][3];
    f32x4  biasf[4];
    for (int g = 0; g < 4; ++g) {
        const float scale = (g == 2) ? -TWO_LOG2E : -LOG2E;
        const int col = g * 64 + jw;
        {
            const float* wr = W_ih + col * I_SZ + quad * 8;
            short8 f;
            #pragma unroll
            for (int e = 0; e < 8; ++e) f[e] = f2bf_rne(scale * wr[e]);
            bfrag[g][0] = f;
        }
        #pragma unroll
        for (int kt = 1; kt < 3; ++kt) {
            const float* wr = W_hh + col * H_SZ + (kt - 1) * 32 + quad * 8;
            short8 f;
            #pragma unroll
            for (int e = 0; e < 8; ++e) f[e] = f2bf_rne(scale * wr[e]);
            bfrag[g][kt] = f;
        }
        const float bg = scale * (b_ih[col] + b_hh[col]);
        biasf[g] = (f32x4){bg, bg, bg, bg};
    }

    // ---- zero h buffers (h0 = 0)
    for (int q = tid; q < 2 * BR * HS; q += 256) ((short*)hbuf)[q] = (short)0;

    // ---- x machinery: lane owns x[b0+nlow][t][quad*8 .. +7] (A row = nlow).
    const float* xb = x + ((size_t)(b0 + nlow) * T_LEN) * I_SZ + quad * 8;

    float4 nx[16];                        // next-chunk fp32 (8 steps x 8 floats)
    short8 sc[8];                         // current-chunk bf16 fragments
    #pragma unroll
    for (int s = 0; s < 8; ++s) {
        nx[2*s]   = *(const float4*)(xb + s * I_SZ);
        nx[2*s+1] = *(const float4*)(xb + s * I_SZ + 4);
    }
    #pragma unroll
    for (int s = 0; s < 8; ++s) {
        union { uint4 u; short8 v; } w;
        w.u.x = pk2t(nx[2*s].x,   nx[2*s].y);
        w.u.y = pk2t(nx[2*s].z,   nx[2*s].w);
        w.u.z = pk2t(nx[2*s+1].x, nx[2*s+1].y);
        w.u.w = pk2t(nx[2*s+1].z, nx[2*s+1].w);
        sc[s] = w.v;
    }

    // LDS addresses: read A rows by nlow; write own 4 cell rows at col jw.
    const short* rb[2] = { &hbuf[0][nlow][quad * 8], &hbuf[1][nlow][quad * 8] };
    short*       wb[2] = { &hbuf[0][rbase][jw],      &hbuf[1][rbase][jw] };

    f32x4 cc = {0.f, 0.f, 0.f, 0.f};
    f32x4 hh = {0.f, 0.f, 0.f, 0.f};

    // ---- x-projection pipeline: preacc[g] holds MFMA(ax_t, Wih, bias)
    // for the UPCOMING step, computed one step early (independent filler).
    f32x4 preacc[4];
    #pragma unroll
    for (int g = 0; g < 4; ++g)
        preacc[g] = __builtin_amdgcn_mfma_f32_16x16x32_bf16(sc[0], bfrag[g][0], biasf[g], 0, 0, 0);

    for (int ch = 0; ch < 32; ++ch) {
        #pragma unroll
        for (int tc = 0; tc < 8; ++tc) {
            const int t = ch * 8 + tc;

            __syncthreads();             // h_{t-1} (and at t=0 the zeroing) visible

            // h fragments: A[m = nlow][k = 32*kt + quad*8 + e]
            const short* hr = rb[t & 1];
            short8 a1 = *(const short8*)(hr);        // h cols  0..31
            short8 a2 = *(const short8*)(hr + 32);   // h cols 32..63

            // issue next chunk's global loads early in the chunk
            if (tc == 0 && ch + 1 < 32) {
                const float* nxt = xb + (t + 8) * I_SZ;
                #pragma unroll
                for (int s = 0; s < 8; ++s) {
                    nx[2*s]   = *(const float4*)(nxt + s * I_SZ);
                    nx[2*s+1] = *(const float4*)(nxt + s * I_SZ + 4);
                }
            }

            // post-barrier dependent chain: only 2 MFMAs deep (C = preacc).
            f32x4 acc[4];
            #pragma unroll
            for (int g = 0; g < 4; ++g) {
                f32x4 a = __builtin_amdgcn_mfma_f32_16x16x32_bf16(a1, bfrag[g][1], preacc[g], 0, 0, 0);
                a = __builtin_amdgcn_mfma_f32_16x16x32_bf16(a2, bfrag[g][2], a, 0, 0, 0);
                acc[g] = a;
            }

            // convert next chunk once its loads landed (7 steps of cover);
            // must precede preacc computation at tc==7 (it reads sc[0]).
            if (tc == 7 && ch + 1 < 32) {
                #pragma unroll
                for (int s = 0; s < 8; ++s) {
                    union { uint4 u; short8 v; } w;
                    w.u.x = pk2t(nx[2*s].x,   nx[2*s].y);
                    w.u.y = pk2t(nx[2*s].z,   nx[2*s].w);
                    w.u.z = pk2t(nx[2*s+1].x, nx[2*s+1].y);
                    w.u.w = pk2t(nx[2*s+1].z, nx[2*s+1].w);
                    sc[s] = w.v;
                }
            }

            // x-projection for step t+1: independent of h -> pure filler
            // under the activation trans chains. (Last step: harmless junk.)
            const short8 nax = sc[(tc + 1) & 7];
            #pragma unroll
            for (int g = 0; g < 4; ++g)
                preacc[g] = __builtin_amdgcn_mfma_f32_16x16x32_bf16(nax, bfrag[g][0], biasf[g], 0, 0, 0);

            // ---- cell update: 4 cells/lane, exp2-ready gate args.
            // acc[0]=-log2e*i, acc[1]=-log2e*f, acc[2]=-2log2e*g, acc[3]=-log2e*o
            f32x4 ei = exp2_4(acc[0]);
            f32x4 ef = exp2_4(acc[1]);
            f32x4 eg = exp2_4(clamp4(acc[2], -ECLAMP, ECLAMP));
            f32x4 eo = exp2_4(acc[3]);
            f32x4 fv = rcp4(ef + 1.0f);                            // sigmoid(f)
            f32x4 ig = (1.0f - eg) * rcp4((ei + 1.0f) * (eg + 1.0f)); // sig(i)*tanh(g)
            cc = fma4(fv, cc, ig);
            f32x4 ec = exp2_4(clamp4(cc * (-TWO_LOG2E), -ECLAMP, ECLAMP));
            hh = (1.0f - ec) * rcp4((eo + 1.0f) * (ec + 1.0f));    // sig(o)*tanh(c)

            // h store: truncation pack, 4x ds_write_b16
            short* hw = wb[(t + 1) & 1];
            hw[0 * HS] = (short)((fbits(hh.x) + 0x8000u) >> 16);
            hw[1 * HS] = (short)((fbits(hh.y) + 0x8000u) >> 16);
            hw[2 * HS] = (short)((fbits(hh.z) + 0x8000u) >> 16);
            hw[3 * HS] = (short)((fbits(hh.w) + 0x8000u) >> 16);
        }
    }

    // ---- epilogue: out[b0+r][o] = h_T[r] . W_fc[o] + b_fc[o]  (fp32 h)
    Hf[rbase + 0][jw] = hh.x;
    Hf[rbase + 1][jw] = hh.y;
    Hf[rbase + 2][jw] = hh.z;
    Hf[rbase + 3][jw] = hh.w;
    __syncthreads();

    if (tid < BR * O_SZ) {               // 128 threads
        const int r = tid >> 3;
        const int o = tid & 7;
        const float* wf = W_fc + o * H_SZ;
        float acc = b_fc[o];
        #pragma unroll
        for (int jx = 0; jx < H_SZ; ++jx) acc += Hf[r][jx] * wf[jx];
        out[(size_t)(b0 + r) * O_SZ + o] = acc;
    }
}

extern "C" void kernel_launch(void* const* d_in, const int* in_sizes, int n_in,
                              void* d_out, int out_size, void* d_ws, size_t ws_size,
                              hipStream_t stream) {
    const float* x    = (const float*)d_in[0];
    const float* W_ih = (const float*)d_in[1];
    const float* W_hh = (const float*)d_in[2];
    const float* b_ih = (const float*)d_in[3];
    const float* b_hh = (const float*)d_in[4];
    const float* W_fc = (const float*)d_in[5];
    const float* b_fc = (const float*)d_in[6];
    float* out = (float*)d_out;

    const int B = 4096;
    lstm_fused_kernel<<<dim3(B / BR), dim3(256), 0, stream>>>(
        x, W_ih, W_hh, b_ih, b_hh, W_fc, b_fc, out);
}